// Round 3
// baseline (264.610 us; speedup 1.0000x reference)
//
#include <hip/hip_runtime.h>

// RoIBridge: positional-embedding expansion per bbox coordinate, masked by
// obj_vec==1, dense [B*T, 256] fp32 output. B=2048, T=128, D=64, IMG=224.
//
// R10 (single variable vs R9): PROLOGUE-HOISTED INPUTS -> uninterrupted
// store stream. rocprof showed the timed graph = 1GB re-poison fill
// (~166us @ 6.5 TB/s) + kernel (~96us @ only 2.9 TB/s for a 268MB store
// stream). Theory: R9's per-iteration prefetch loads sit BETWEEN store
// bursts in program order; vmcnt retires in-order, so waiting on loads
// forces retiring all earlier stores, whose retirement is gated by HBM
// drain. Fix: load ALL inputs first (obj -> one 64-bit ballot mask in
// SGPRs; frac -> 32-entry per-lane VGPR array), fence, then 32x{compute +
// 1KB store} with ZERO s_waitcnt after the prologue -- shape-identical to
// the fill kernel that hits 80% peak at 10% occupancy.
// Carries forward: in-register sinusoid via hw v_sin/v_cos in revolutions
// (R8), 2048-block persistent-style launch (R9).
// [R11, R12 = R10 resubmitted verbatim: both benches died on
//  GPUAcquisitionTimeout (broker at capacity), no measurement taken.]
//
// table[pos,i] = sin(pos * 10000^(-floor(i/2)/32)) even i, cos odd i.
// rev = fract(pos*scale/2pi): integer-revolution shift preserves sin/cos.
// absmax ~2e-3 vs 2e-2 threshold (verified R8).

#define ROI_ROWS  (2048 * 128)       // B*T = 262,144
#define ROI_IMG   224.0f
#define RPW_TOT   32                 // rows per wave, all contiguous
#define BLOCKS    2048               // 8192 waves x 32 rows = 262,144 exact
#define WAVES     (BLOCKS * 4)

typedef float vfloat4 __attribute__((ext_vector_type(4)));

__global__ __launch_bounds__(256) void RoIBridge_kernel(
    const float* __restrict__ bboxs,   // [ROWS*4]
    const int*   __restrict__ objs,    // [ROWS]
    const float* __restrict__ table,   // unused (recomputed in-register)
    vfloat4*     __restrict__ out)     // [ROWS*64] float4s
{
    (void)table;
    const int gwave = blockIdx.x * 4 + (threadIdx.x >> 6);
    const int lane  = threadIdx.x & 63;
    const int c     = lane >> 4;       // coord 0..3 (16 lanes each)
    const int d4    = lane & 15;       // float4 within 64-float embedding

    // Per-thread frequency constants (revolutions per unit pos).
    const float L      = 0.41524101186092029f;   // log2(10000)/32
    const float INV2PI = 0.15915494309189535f;   // 1/(2pi)
    const float fi0 = (float)(d4 * 2);
    const float s0 = exp2f(-fi0 * L) * INV2PI;
    const float s1 = exp2f(-(fi0 + 1.0f) * L) * INV2PI;

    const int rowbase = gwave * RPW_TOT;

    // ---- Prologue: ALL input loads, before any store ----
    // obj flags: lanes 0..31 cover the wave's 32 rows (lanes 32..63
    // duplicate them; only bits 0..31 of the ballot are consumed).
    const int j31 = lane & 31;
    const unsigned long long omask = __ballot(objs[rowbase + j31] == 1);

    // frac: each lane keeps its own coordinate c for all 32 rows.
    // Indexed only by compile-time constants -> stays in VGPRs.
    float frac[RPW_TOT];
#pragma unroll
    for (int j = 0; j < RPW_TOT; ++j)
        frac[j] = bboxs[((rowbase + j) << 2) + c];

    // Fence: forbid the compiler from re-sinking input loads into the
    // store stream (IR-level memory fence + MIR-level sched fence).
    asm volatile("" ::: "memory");
    __builtin_amdgcn_sched_barrier(0);

    const vfloat4 z = (vfloat4){0.0f, 0.0f, 0.0f, 0.0f};

    // ---- Pure store stream: no vmem reads, no s_waitcnt ----
#pragma unroll
    for (int j = 0; j < RPW_TOT; ++j) {
        float v = fminf(fmaxf(frac[j] * ROI_IMG, 0.0f), ROI_IMG);
        const float pos = (float)(int)v;        // trunc, exact small int
        const float r0 = __builtin_amdgcn_fractf(pos * s0);
        const float r1 = __builtin_amdgcn_fractf(pos * s1);
        vfloat4 e;
        e.x = __builtin_amdgcn_sinf(r0);
        e.y = __builtin_amdgcn_cosf(r0);
        e.z = __builtin_amdgcn_sinf(r1);
        e.w = __builtin_amdgcn_cosf(r1);
        const bool o = (omask >> j) & 1ull;     // wave-uniform SGPR test
        out[(rowbase + j) * 64 + lane] = o ? e : z;
    }
}

extern "C" void kernel_launch(void* const* d_in, const int* in_sizes, int n_in,
                              void* d_out, int out_size, void* d_ws, size_t ws_size,
                              hipStream_t stream) {
    const float* bboxs = (const float*)d_in[0];   // [2048,128,4] fp32
    const int*   objs  = (const int*)d_in[1];     // [2048,128] int32
    const float* table = (const float*)d_in[2];   // [225,64] fp32 (unused)
    vfloat4* out = (vfloat4*)d_out;               // [262144*64] float4

    RoIBridge_kernel<<<BLOCKS, 256, 0, stream>>>(bboxs, objs, table, out);
}